// Round 1
// baseline (1047.075 us; speedup 1.0000x reference)
//
#include <hip/hip_runtime.h>
#include <math.h>

// ---------------------------------------------------------------------------
// GAT 3-layer net. Strategy: build CSR by dst once per call; per-layer:
//   gemm (h = X@W), al (al_s/al_d = h@a), agg (per-dst wave softmax+gather).
// All fp32. No float atomics in the main path.
// ---------------------------------------------------------------------------

__global__ __launch_bounds__(256) void k_count(const int* __restrict__ ei,
                                               int* __restrict__ cnt, int E, int N) {
  int i = blockIdx.x * 256 + threadIdx.x;
  int tot = E + N;
  if (i >= tot) return;
  int dst = (i < E) ? ei[E + i] : (i - E);
  atomicAdd(&cnt[dst], 1);
}

// single-block blocked scan: 1024 threads, each owns a contiguous chunk
__global__ __launch_bounds__(1024) void k_scan(const int* __restrict__ cnt,
                                               int* __restrict__ rowp, int n) {
  __shared__ int sm[1024];
  int tid = threadIdx.x;
  int CH = (n + 1023) >> 10;
  int b = tid * CH, e = b + CH;
  if (b > n) b = n;
  if (e > n) e = n;
  int s = 0;
  for (int i = b; i < e; ++i) s += cnt[i];
  sm[tid] = s;
  __syncthreads();
  for (int off = 1; off < 1024; off <<= 1) {
    int t = (tid >= off) ? sm[tid - off] : 0;
    __syncthreads();
    sm[tid] += t;
    __syncthreads();
  }
  int run = sm[tid] - s;  // exclusive prefix of this chunk
  for (int i = b; i < e; ++i) { rowp[i] = run; run += cnt[i]; }
  if (tid == 1023) rowp[n] = run;
}

__global__ __launch_bounds__(256) void k_copy(const int* __restrict__ a,
                                              int* __restrict__ b, int n) {
  int i = blockIdx.x * 256 + threadIdx.x;
  if (i < n) b[i] = a[i];
}

__global__ __launch_bounds__(256) void k_scatter(const int* __restrict__ ei,
                                                 int* __restrict__ cursor,
                                                 int* __restrict__ csr_src, int E, int N) {
  int i = blockIdx.x * 256 + threadIdx.x;
  int tot = E + N;
  if (i >= tot) return;
  int src, dst;
  if (i < E) { src = ei[i]; dst = ei[E + i]; }
  else       { src = i - E; dst = i - E; }
  int pos = atomicAdd(&cursor[dst], 1);
  csr_src[pos] = src;
}

// layer-1 GEMM: X [N,4] @ W [4,128]
__global__ __launch_bounds__(256) void k_gemm4(const float* __restrict__ X,
                                               const float* __restrict__ W,
                                               float* __restrict__ Hout, int N) {
  int idx = blockIdx.x * 256 + threadIdx.x;
  if (idx >= N * 128) return;
  int n = idx >> 7, j = idx & 127;
  float4 xv = *(const float4*)(X + n * 4);
  float h = xv.x * W[j] + xv.y * W[128 + j] + xv.z * W[256 + j] + xv.w * W[384 + j];
  Hout[idx] = h;
}

// GEMM: X [N,128] @ W [128,128] -> Hout [N,128]
// block = 256 threads, tile = 64 rows x 128 cols, 4x8 microtile per thread.
// K chunked by 64 to keep LDS <= 50 KB (3 blocks/CU possible).
__global__ __launch_bounds__(256) void k_gemm128(const float* __restrict__ X,
                                                 const float* __restrict__ W,
                                                 float* __restrict__ Hout, int N) {
  __shared__ float Ws[64 * 128];    // 32 KB  (k-chunk x 128 cols)
  __shared__ float Xs[64 * 68];     // 17 KB  (64 rows x k-chunk, pad 68)
  int tid = threadIdx.x;
  int base = blockIdx.x * 64;
  int ty = tid >> 4, tx = tid & 15;

  float acc[4][8];
#pragma unroll
  for (int r = 0; r < 4; ++r)
#pragma unroll
    for (int c = 0; c < 8; ++c) acc[r][c] = 0.f;

  for (int kk = 0; kk < 128; kk += 64) {
    __syncthreads();  // protect previous chunk's reads
    // load W chunk: rows kk..kk+63 are contiguous floats
    for (int i = tid * 4; i < 64 * 128; i += 1024) {
      *(float4*)(Ws + i) = *(const float4*)(W + kk * 128 + i);
    }
    // load X tile chunk: 64 nodes x 64 feats
    for (int i = tid; i < 64 * 16; i += 256) {
      int node = i >> 4, k4 = (i & 15) << 2;
      int gn = base + node;
      float4 v;
      if (gn < N) v = *(const float4*)(X + gn * 128 + kk + k4);
      else        v = make_float4(0.f, 0.f, 0.f, 0.f);
      *(float4*)(Xs + node * 68 + k4) = v;
    }
    __syncthreads();

    for (int k = 0; k < 64; ++k) {
      float a0 = Xs[(ty * 4 + 0) * 68 + k];
      float a1 = Xs[(ty * 4 + 1) * 68 + k];
      float a2 = Xs[(ty * 4 + 2) * 68 + k];
      float a3 = Xs[(ty * 4 + 3) * 68 + k];
      float4 b0 = *(const float4*)(Ws + k * 128 + tx * 8);
      float4 b1 = *(const float4*)(Ws + k * 128 + tx * 8 + 4);
      acc[0][0] += a0 * b0.x; acc[0][1] += a0 * b0.y; acc[0][2] += a0 * b0.z; acc[0][3] += a0 * b0.w;
      acc[0][4] += a0 * b1.x; acc[0][5] += a0 * b1.y; acc[0][6] += a0 * b1.z; acc[0][7] += a0 * b1.w;
      acc[1][0] += a1 * b0.x; acc[1][1] += a1 * b0.y; acc[1][2] += a1 * b0.z; acc[1][3] += a1 * b0.w;
      acc[1][4] += a1 * b1.x; acc[1][5] += a1 * b1.y; acc[1][6] += a1 * b1.z; acc[1][7] += a1 * b1.w;
      acc[2][0] += a2 * b0.x; acc[2][1] += a2 * b0.y; acc[2][2] += a2 * b0.z; acc[2][3] += a2 * b0.w;
      acc[2][4] += a2 * b1.x; acc[2][5] += a2 * b1.y; acc[2][6] += a2 * b1.z; acc[2][7] += a2 * b1.w;
      acc[3][0] += a3 * b0.x; acc[3][1] += a3 * b0.y; acc[3][2] += a3 * b0.z; acc[3][3] += a3 * b0.w;
      acc[3][4] += a3 * b1.x; acc[3][5] += a3 * b1.y; acc[3][6] += a3 * b1.z; acc[3][7] += a3 * b1.w;
    }
  }

#pragma unroll
  for (int r = 0; r < 4; ++r) {
    int gn = base + ty * 4 + r;
    if (gn < N) {
      float4 o0 = make_float4(acc[r][0], acc[r][1], acc[r][2], acc[r][3]);
      float4 o1 = make_float4(acc[r][4], acc[r][5], acc[r][6], acc[r][7]);
      *(float4*)(Hout + gn * 128 + tx * 8) = o0;
      *(float4*)(Hout + gn * 128 + tx * 8 + 4) = o1;
    }
  }
}

// per-node attention logits: al_s = h . a_src, al_d = h . a_dst  (one wave/node)
__global__ __launch_bounds__(256) void k_al(const float* __restrict__ Hh,
                                            const float* __restrict__ asv,
                                            const float* __restrict__ adv,
                                            float* __restrict__ al_s,
                                            float* __restrict__ al_d, int N) {
  int wid = threadIdx.x >> 6, lane = threadIdx.x & 63;
  int node = blockIdx.x * 4 + wid;
  if (node >= N) return;
  float2 h = *(const float2*)(Hh + node * 128 + lane * 2);
  float2 s2 = *(const float2*)(asv + lane * 2);
  float2 d2 = *(const float2*)(adv + lane * 2);
  float ps = h.x * s2.x + h.y * s2.y;
  float pd = h.x * d2.x + h.y * d2.y;
  for (int off = 32; off; off >>= 1) {
    ps += __shfl_xor(ps, off);
    pd += __shfl_xor(pd, off);
  }
  if (lane == 0) { al_s[node] = ps; al_d[node] = pd; }
}

// per-dst softmax + aggregation. one wave per dst node; lane owns 2 features.
__global__ __launch_bounds__(256) void k_agg(const int* __restrict__ csr_src,
                                             const int* __restrict__ rowp,
                                             const float* __restrict__ al_s,
                                             const float* __restrict__ al_d,
                                             const float* __restrict__ Hh,
                                             const float* __restrict__ bias,
                                             float* __restrict__ Yout, int N, int relu) {
  int wid = threadIdx.x >> 6, lane = threadIdx.x & 63;
  int dst = blockIdx.x * 4 + wid;
  if (dst >= N) return;
  int beg = rowp[dst], end = rowp[dst + 1];
  float ald = al_d[dst];

  float m = -INFINITY;
  for (int j = beg + lane; j < end; j += 64) {
    float e = al_s[csr_src[j]] + ald;
    e = (e > 0.f) ? e : 0.2f * e;
    m = fmaxf(m, e);
  }
  for (int off = 32; off; off >>= 1) m = fmaxf(m, __shfl_xor(m, off));

  float den = 0.f;
  for (int j = beg + lane; j < end; j += 64) {
    float e = al_s[csr_src[j]] + ald;
    e = (e > 0.f) ? e : 0.2f * e;
    den += expf(e - m);
  }
  for (int off = 32; off; off >>= 1) den += __shfl_xor(den, off);
  float inv = 1.0f / (den + 1e-16f);

  float2 acc = {0.f, 0.f};
  for (int j = beg; j < end; ++j) {
    int s = csr_src[j];
    float e = al_s[s] + ald;
    e = (e > 0.f) ? e : 0.2f * e;
    float w = expf(e - m) * inv;
    float2 hv = *(const float2*)(Hh + s * 128 + lane * 2);
    acc.x += w * hv.x;
    acc.y += w * hv.y;
  }
  float2 bv = *(const float2*)(bias + lane * 2);
  float2 o = {acc.x + bv.x, acc.y + bv.y};
  if (relu) { o.x = fmaxf(o.x, 0.f); o.y = fmaxf(o.y, 0.f); }
  *(float2*)(Yout + dst * 128 + lane * 2) = o;
}

__global__ __launch_bounds__(256) void k_pool(const float* __restrict__ Hh,
                                              const int* __restrict__ batch,
                                              float* __restrict__ gsum,
                                              float* __restrict__ gcnt, int N) {
  int wid = threadIdx.x >> 6, lane = threadIdx.x & 63;
  int node = blockIdx.x * 4 + wid;
  if (node >= N) return;
  int g = batch[node];
  float2 h = *(const float2*)(Hh + node * 128 + lane * 2);
  atomicAdd(&gsum[g * 128 + lane * 2], h.x);
  atomicAdd(&gsum[g * 128 + lane * 2 + 1], h.y);
  if (lane == 0) atomicAdd(&gcnt[g], 1.0f);
}

__global__ __launch_bounds__(128) void k_final(const float* __restrict__ gsum,
                                               const float* __restrict__ gcnt,
                                               const float* __restrict__ Wlin,
                                               const float* __restrict__ blin,
                                               float* __restrict__ out) {
  int t = threadIdx.x;  // 128 threads: (g, c) pairs
  int g = t >> 1, c = t & 1;
  float inv = 1.0f / fmaxf(gcnt[g], 1.0f);
  float acc = blin[c];
  for (int k = 0; k < 128; ++k) acc += gsum[g * 128 + k] * inv * Wlin[k * 2 + c];
  out[g * 2 + c] = acc;
}

extern "C" void kernel_launch(void* const* d_in, const int* in_sizes, int n_in,
                              void* d_out, int out_size, void* d_ws, size_t ws_size,
                              hipStream_t stream) {
  const float* x    = (const float*)d_in[0];
  const int*   ei   = (const int*)d_in[1];
  const int*   batch= (const int*)d_in[2];
  const float* W1   = (const float*)d_in[3];
  const float* as1  = (const float*)d_in[4];
  const float* ad1  = (const float*)d_in[5];
  const float* b1   = (const float*)d_in[6];
  const float* W2   = (const float*)d_in[7];
  const float* as2  = (const float*)d_in[8];
  const float* ad2  = (const float*)d_in[9];
  const float* b2   = (const float*)d_in[10];
  const float* W3   = (const float*)d_in[11];
  const float* as3  = (const float*)d_in[12];
  const float* ad3  = (const float*)d_in[13];
  const float* b3   = (const float*)d_in[14];
  const float* Wlin = (const float*)d_in[15];
  const float* blin = (const float*)d_in[16];

  int N = in_sizes[0] / 4;
  int E = in_sizes[1] / 2;
  int ET = E + N;

  char* ws = (char*)d_ws;
  float* bufA = (float*)ws; ws += (size_t)N * 128 * 4;
  float* bufB = (float*)ws; ws += (size_t)N * 128 * 4;
  float* al_s = (float*)ws; ws += (size_t)N * 4;
  float* al_d = (float*)ws; ws += (size_t)N * 4;
  float* gsum = (float*)ws; ws += (size_t)64 * 128 * 4;
  float* gcnt = (float*)ws; ws += (size_t)64 * 4;
  int* rowp   = (int*)ws;   ws += (size_t)(N + 1) * 4;
  int* cursor = (int*)ws;   ws += (size_t)N * 4;
  int* csr    = (int*)ws;   ws += (size_t)ET * 4;

  hipMemsetAsync(cursor, 0, (size_t)N * 4, stream);
  hipMemsetAsync(gsum, 0, (size_t)(64 * 128 + 64) * 4, stream);  // gsum + gcnt

  int eb = (ET + 255) / 256;
  k_count  <<<eb, 256, 0, stream>>>(ei, cursor, E, N);
  k_scan   <<<1, 1024, 0, stream>>>(cursor, rowp, N);
  k_copy   <<<(N + 255) / 256, 256, 0, stream>>>(rowp, cursor, N);
  k_scatter<<<eb, 256, 0, stream>>>(ei, cursor, csr, E, N);

  int nb4 = (N + 3) / 4;
  // layer 1
  k_gemm4<<<(N * 128 + 255) / 256, 256, 0, stream>>>(x, W1, bufA, N);
  k_al   <<<nb4, 256, 0, stream>>>(bufA, as1, ad1, al_s, al_d, N);
  k_agg  <<<nb4, 256, 0, stream>>>(csr, rowp, al_s, al_d, bufA, b1, bufB, N, 1);
  // layer 2
  k_gemm128<<<(N + 63) / 64, 256, 0, stream>>>(bufB, W2, bufA, N);
  k_al     <<<nb4, 256, 0, stream>>>(bufA, as2, ad2, al_s, al_d, N);
  k_agg    <<<nb4, 256, 0, stream>>>(csr, rowp, al_s, al_d, bufA, b2, bufB, N, 1);
  // layer 3
  k_gemm128<<<(N + 63) / 64, 256, 0, stream>>>(bufB, W3, bufA, N);
  k_al     <<<nb4, 256, 0, stream>>>(bufA, as3, ad3, al_s, al_d, N);
  k_agg    <<<nb4, 256, 0, stream>>>(csr, rowp, al_s, al_d, bufA, b3, bufB, N, 0);

  // global mean pool + linear head
  k_pool <<<nb4, 256, 0, stream>>>(bufB, batch, gsum, gcnt, N);
  k_final<<<1, 128, 0, stream>>>(gsum, gcnt, Wlin, blin, (float*)d_out);
}

// Round 2
// 714.539 us; speedup vs baseline: 1.4654x; 1.4654x over previous
//
#include <hip/hip_runtime.h>
#include <math.h>

// ---------------------------------------------------------------------------
// GAT 3-layer net. Strategy: build CSR by dst once per call; per-layer:
//   gemm (h = X@W), al (al_s/al_d = h@a), agg (per-dst wave softmax+gather).
// All fp32. No float atomics in the main path.
// R1: k_pool rewritten as run-length segment accumulation (batch is sorted):
//     ~2 atomic flushes per wave instead of per-node atomics (781-way
//     contention caused 362us / 51MB of atomic write traffic).
// ---------------------------------------------------------------------------

__global__ __launch_bounds__(256) void k_count(const int* __restrict__ ei,
                                               int* __restrict__ cnt, int E, int N) {
  int i = blockIdx.x * 256 + threadIdx.x;
  int tot = E + N;
  if (i >= tot) return;
  int dst = (i < E) ? ei[E + i] : (i - E);
  atomicAdd(&cnt[dst], 1);
}

// single-block blocked scan: 1024 threads, each owns a contiguous chunk
__global__ __launch_bounds__(1024) void k_scan(const int* __restrict__ cnt,
                                               int* __restrict__ rowp, int n) {
  __shared__ int sm[1024];
  int tid = threadIdx.x;
  int CH = (n + 1023) >> 10;
  int b = tid * CH, e = b + CH;
  if (b > n) b = n;
  if (e > n) e = n;
  int s = 0;
  for (int i = b; i < e; ++i) s += cnt[i];
  sm[tid] = s;
  __syncthreads();
  for (int off = 1; off < 1024; off <<= 1) {
    int t = (tid >= off) ? sm[tid - off] : 0;
    __syncthreads();
    sm[tid] += t;
    __syncthreads();
  }
  int run = sm[tid] - s;  // exclusive prefix of this chunk
  for (int i = b; i < e; ++i) { rowp[i] = run; run += cnt[i]; }
  if (tid == 1023) rowp[n] = run;
}

__global__ __launch_bounds__(256) void k_copy(const int* __restrict__ a,
                                              int* __restrict__ b, int n) {
  int i = blockIdx.x * 256 + threadIdx.x;
  if (i < n) b[i] = a[i];
}

__global__ __launch_bounds__(256) void k_scatter(const int* __restrict__ ei,
                                                 int* __restrict__ cursor,
                                                 int* __restrict__ csr_src, int E, int N) {
  int i = blockIdx.x * 256 + threadIdx.x;
  int tot = E + N;
  if (i >= tot) return;
  int src, dst;
  if (i < E) { src = ei[i]; dst = ei[E + i]; }
  else       { src = i - E; dst = i - E; }
  int pos = atomicAdd(&cursor[dst], 1);
  csr_src[pos] = src;
}

// layer-1 GEMM: X [N,4] @ W [4,128]
__global__ __launch_bounds__(256) void k_gemm4(const float* __restrict__ X,
                                               const float* __restrict__ W,
                                               float* __restrict__ Hout, int N) {
  int idx = blockIdx.x * 256 + threadIdx.x;
  if (idx >= N * 128) return;
  int n = idx >> 7, j = idx & 127;
  float4 xv = *(const float4*)(X + n * 4);
  float h = xv.x * W[j] + xv.y * W[128 + j] + xv.z * W[256 + j] + xv.w * W[384 + j];
  Hout[idx] = h;
}

// GEMM: X [N,128] @ W [128,128] -> Hout [N,128]
// block = 256 threads, tile = 64 rows x 128 cols, 4x8 microtile per thread.
// K chunked by 64 to keep LDS <= 50 KB (3 blocks/CU possible).
__global__ __launch_bounds__(256) void k_gemm128(const float* __restrict__ X,
                                                 const float* __restrict__ W,
                                                 float* __restrict__ Hout, int N) {
  __shared__ float Ws[64 * 128];    // 32 KB  (k-chunk x 128 cols)
  __shared__ float Xs[64 * 68];     // 17 KB  (64 rows x k-chunk, pad 68)
  int tid = threadIdx.x;
  int base = blockIdx.x * 64;
  int ty = tid >> 4, tx = tid & 15;

  float acc[4][8];
#pragma unroll
  for (int r = 0; r < 4; ++r)
#pragma unroll
    for (int c = 0; c < 8; ++c) acc[r][c] = 0.f;

  for (int kk = 0; kk < 128; kk += 64) {
    __syncthreads();  // protect previous chunk's reads
    // load W chunk: rows kk..kk+63 are contiguous floats
    for (int i = tid * 4; i < 64 * 128; i += 1024) {
      *(float4*)(Ws + i) = *(const float4*)(W + kk * 128 + i);
    }
    // load X tile chunk: 64 nodes x 64 feats
    for (int i = tid; i < 64 * 16; i += 256) {
      int node = i >> 4, k4 = (i & 15) << 2;
      int gn = base + node;
      float4 v;
      if (gn < N) v = *(const float4*)(X + gn * 128 + kk + k4);
      else        v = make_float4(0.f, 0.f, 0.f, 0.f);
      *(float4*)(Xs + node * 68 + k4) = v;
    }
    __syncthreads();

    for (int k = 0; k < 64; ++k) {
      float a0 = Xs[(ty * 4 + 0) * 68 + k];
      float a1 = Xs[(ty * 4 + 1) * 68 + k];
      float a2 = Xs[(ty * 4 + 2) * 68 + k];
      float a3 = Xs[(ty * 4 + 3) * 68 + k];
      float4 b0 = *(const float4*)(Ws + k * 128 + tx * 8);
      float4 b1 = *(const float4*)(Ws + k * 128 + tx * 8 + 4);
      acc[0][0] += a0 * b0.x; acc[0][1] += a0 * b0.y; acc[0][2] += a0 * b0.z; acc[0][3] += a0 * b0.w;
      acc[0][4] += a0 * b1.x; acc[0][5] += a0 * b1.y; acc[0][6] += a0 * b1.z; acc[0][7] += a0 * b1.w;
      acc[1][0] += a1 * b0.x; acc[1][1] += a1 * b0.y; acc[1][2] += a1 * b0.z; acc[1][3] += a1 * b0.w;
      acc[1][4] += a1 * b1.x; acc[1][5] += a1 * b1.y; acc[1][6] += a1 * b1.z; acc[1][7] += a1 * b1.w;
      acc[2][0] += a2 * b0.x; acc[2][1] += a2 * b0.y; acc[2][2] += a2 * b0.z; acc[2][3] += a2 * b0.w;
      acc[2][4] += a2 * b1.x; acc[2][5] += a2 * b1.y; acc[2][6] += a2 * b1.z; acc[2][7] += a2 * b1.w;
      acc[3][0] += a3 * b0.x; acc[3][1] += a3 * b0.y; acc[3][2] += a3 * b0.z; acc[3][3] += a3 * b0.w;
      acc[3][4] += a3 * b1.x; acc[3][5] += a3 * b1.y; acc[3][6] += a3 * b1.z; acc[3][7] += a3 * b1.w;
    }
  }

#pragma unroll
  for (int r = 0; r < 4; ++r) {
    int gn = base + ty * 4 + r;
    if (gn < N) {
      float4 o0 = make_float4(acc[r][0], acc[r][1], acc[r][2], acc[r][3]);
      float4 o1 = make_float4(acc[r][4], acc[r][5], acc[r][6], acc[r][7]);
      *(float4*)(Hout + gn * 128 + tx * 8) = o0;
      *(float4*)(Hout + gn * 128 + tx * 8 + 4) = o1;
    }
  }
}

// per-node attention logits: al_s = h . a_src, al_d = h . a_dst  (one wave/node)
__global__ __launch_bounds__(256) void k_al(const float* __restrict__ Hh,
                                            const float* __restrict__ asv,
                                            const float* __restrict__ adv,
                                            float* __restrict__ al_s,
                                            float* __restrict__ al_d, int N) {
  int wid = threadIdx.x >> 6, lane = threadIdx.x & 63;
  int node = blockIdx.x * 4 + wid;
  if (node >= N) return;
  float2 h = *(const float2*)(Hh + node * 128 + lane * 2);
  float2 s2 = *(const float2*)(asv + lane * 2);
  float2 d2 = *(const float2*)(adv + lane * 2);
  float ps = h.x * s2.x + h.y * s2.y;
  float pd = h.x * d2.x + h.y * d2.y;
  for (int off = 32; off; off >>= 1) {
    ps += __shfl_xor(ps, off);
    pd += __shfl_xor(pd, off);
  }
  if (lane == 0) { al_s[node] = ps; al_d[node] = pd; }
}

// per-dst softmax + aggregation. one wave per dst node; lane owns 2 features.
__global__ __launch_bounds__(256) void k_agg(const int* __restrict__ csr_src,
                                             const int* __restrict__ rowp,
                                             const float* __restrict__ al_s,
                                             const float* __restrict__ al_d,
                                             const float* __restrict__ Hh,
                                             const float* __restrict__ bias,
                                             float* __restrict__ Yout, int N, int relu) {
  int wid = threadIdx.x >> 6, lane = threadIdx.x & 63;
  int dst = blockIdx.x * 4 + wid;
  if (dst >= N) return;
  int beg = rowp[dst], end = rowp[dst + 1];
  float ald = al_d[dst];

  float m = -INFINITY;
  for (int j = beg + lane; j < end; j += 64) {
    float e = al_s[csr_src[j]] + ald;
    e = (e > 0.f) ? e : 0.2f * e;
    m = fmaxf(m, e);
  }
  for (int off = 32; off; off >>= 1) m = fmaxf(m, __shfl_xor(m, off));

  float den = 0.f;
  for (int j = beg + lane; j < end; j += 64) {
    float e = al_s[csr_src[j]] + ald;
    e = (e > 0.f) ? e : 0.2f * e;
    den += expf(e - m);
  }
  for (int off = 32; off; off >>= 1) den += __shfl_xor(den, off);
  float inv = 1.0f / (den + 1e-16f);

  float2 acc = {0.f, 0.f};
  for (int j = beg; j < end; ++j) {
    int s = csr_src[j];
    float e = al_s[s] + ald;
    e = (e > 0.f) ? e : 0.2f * e;
    float w = expf(e - m) * inv;
    float2 hv = *(const float2*)(Hh + s * 128 + lane * 2);
    acc.x += w * hv.x;
    acc.y += w * hv.y;
  }
  float2 bv = *(const float2*)(bias + lane * 2);
  float2 o = {acc.x + bv.x, acc.y + bv.y};
  if (relu) { o.x = fmaxf(o.x, 0.f); o.y = fmaxf(o.y, 0.f); }
  *(float2*)(Yout + dst * 128 + lane * 2) = o;
}

// run-length pooling over sorted batch: each wave owns a contiguous node
// range, accumulates locally, flushes one atomicAdd per graph transition.
__global__ __launch_bounds__(256) void k_pool(const float* __restrict__ Hh,
                                              const int* __restrict__ batch,
                                              float* __restrict__ gsum,
                                              float* __restrict__ gcnt,
                                              int N, int nwaves) {
  int gw = (blockIdx.x * 256 + threadIdx.x) >> 6;
  int lane = threadIdx.x & 63;
  int chunk = (N + nwaves - 1) / nwaves;
  int beg = gw * chunk;
  int end = beg + chunk; if (end > N) end = N;
  if (beg >= end) return;

  int curg = batch[beg];
  float2 acc = {0.f, 0.f};
  int cnt = 0;
  for (int n = beg; n < end; ++n) {
    int g = batch[n];
    if (g != curg) {
      atomicAdd(&gsum[curg * 128 + lane * 2], acc.x);
      atomicAdd(&gsum[curg * 128 + lane * 2 + 1], acc.y);
      if (lane == 0) atomicAdd(&gcnt[curg], (float)cnt);
      acc.x = 0.f; acc.y = 0.f; cnt = 0; curg = g;
    }
    float2 h = *(const float2*)(Hh + (size_t)n * 128 + lane * 2);
    acc.x += h.x; acc.y += h.y; ++cnt;
  }
  atomicAdd(&gsum[curg * 128 + lane * 2], acc.x);
  atomicAdd(&gsum[curg * 128 + lane * 2 + 1], acc.y);
  if (lane == 0) atomicAdd(&gcnt[curg], (float)cnt);
}

__global__ __launch_bounds__(128) void k_final(const float* __restrict__ gsum,
                                               const float* __restrict__ gcnt,
                                               const float* __restrict__ Wlin,
                                               const float* __restrict__ blin,
                                               float* __restrict__ out) {
  int t = threadIdx.x;  // 128 threads: (g, c) pairs
  int g = t >> 1, c = t & 1;
  float inv = 1.0f / fmaxf(gcnt[g], 1.0f);
  float acc = blin[c];
  for (int k = 0; k < 128; ++k) acc += gsum[g * 128 + k] * inv * Wlin[k * 2 + c];
  out[g * 2 + c] = acc;
}

extern "C" void kernel_launch(void* const* d_in, const int* in_sizes, int n_in,
                              void* d_out, int out_size, void* d_ws, size_t ws_size,
                              hipStream_t stream) {
  const float* x    = (const float*)d_in[0];
  const int*   ei   = (const int*)d_in[1];
  const int*   batch= (const int*)d_in[2];
  const float* W1   = (const float*)d_in[3];
  const float* as1  = (const float*)d_in[4];
  const float* ad1  = (const float*)d_in[5];
  const float* b1   = (const float*)d_in[6];
  const float* W2   = (const float*)d_in[7];
  const float* as2  = (const float*)d_in[8];
  const float* ad2  = (const float*)d_in[9];
  const float* b2   = (const float*)d_in[10];
  const float* W3   = (const float*)d_in[11];
  const float* as3  = (const float*)d_in[12];
  const float* ad3  = (const float*)d_in[13];
  const float* b3   = (const float*)d_in[14];
  const float* Wlin = (const float*)d_in[15];
  const float* blin = (const float*)d_in[16];

  int N = in_sizes[0] / 4;
  int E = in_sizes[1] / 2;
  int ET = E + N;

  char* ws = (char*)d_ws;
  float* bufA = (float*)ws; ws += (size_t)N * 128 * 4;
  float* bufB = (float*)ws; ws += (size_t)N * 128 * 4;
  float* al_s = (float*)ws; ws += (size_t)N * 4;
  float* al_d = (float*)ws; ws += (size_t)N * 4;
  float* gsum = (float*)ws; ws += (size_t)64 * 128 * 4;
  float* gcnt = (float*)ws; ws += (size_t)64 * 4;
  int* rowp   = (int*)ws;   ws += (size_t)(N + 1) * 4;
  int* cursor = (int*)ws;   ws += (size_t)N * 4;
  int* csr    = (int*)ws;   ws += (size_t)ET * 4;

  hipMemsetAsync(cursor, 0, (size_t)N * 4, stream);
  hipMemsetAsync(gsum, 0, (size_t)(64 * 128 + 64) * 4, stream);  // gsum + gcnt

  int eb = (ET + 255) / 256;
  k_count  <<<eb, 256, 0, stream>>>(ei, cursor, E, N);
  k_scan   <<<1, 1024, 0, stream>>>(cursor, rowp, N);
  k_copy   <<<(N + 255) / 256, 256, 0, stream>>>(rowp, cursor, N);
  k_scatter<<<eb, 256, 0, stream>>>(ei, cursor, csr, E, N);

  int nb4 = (N + 3) / 4;
  // layer 1
  k_gemm4<<<(N * 128 + 255) / 256, 256, 0, stream>>>(x, W1, bufA, N);
  k_al   <<<nb4, 256, 0, stream>>>(bufA, as1, ad1, al_s, al_d, N);
  k_agg  <<<nb4, 256, 0, stream>>>(csr, rowp, al_s, al_d, bufA, b1, bufB, N, 1);
  // layer 2
  k_gemm128<<<(N + 63) / 64, 256, 0, stream>>>(bufB, W2, bufA, N);
  k_al     <<<nb4, 256, 0, stream>>>(bufA, as2, ad2, al_s, al_d, N);
  k_agg    <<<nb4, 256, 0, stream>>>(csr, rowp, al_s, al_d, bufA, b2, bufB, N, 1);
  // layer 3
  k_gemm128<<<(N + 63) / 64, 256, 0, stream>>>(bufB, W3, bufA, N);
  k_al     <<<nb4, 256, 0, stream>>>(bufA, as3, ad3, al_s, al_d, N);
  k_agg    <<<nb4, 256, 0, stream>>>(csr, rowp, al_s, al_d, bufA, b3, bufB, N, 0);

  // global mean pool + linear head (256 blocks x 4 waves = 1024 waves)
  k_pool <<<256, 256, 0, stream>>>(bufB, batch, gsum, gcnt, N, 1024);
  k_final<<<1, 128, 0, stream>>>(gsum, gcnt, Wlin, blin, (float*)d_out);
}

// Round 3
// 593.418 us; speedup vs baseline: 1.7645x; 1.2041x over previous
//
#include <hip/hip_runtime.h>
#include <math.h>

// ---------------------------------------------------------------------------
// GAT 3-layer net. CSR by dst built once per call; per-layer:
//   gemm (h = X@W), al (al_s/al_d = h@a), agg (per-dst wave softmax+gather).
// R1: k_pool run-length accumulation (batch sorted) — 362us -> ~5us.
// R2: k_agg 3-pass with per-edge scratch: pass A stores leaky-relu e
//     (kills 2nd al_s gather pass), pass B stores exp (kills 64x-redundant
//     per-lane expf in pass C), pass C unrolled x4 for gather MLP.
// ---------------------------------------------------------------------------

__global__ __launch_bounds__(256) void k_count(const int* __restrict__ ei,
                                               int* __restrict__ cnt, int E, int N) {
  int i = blockIdx.x * 256 + threadIdx.x;
  int tot = E + N;
  if (i >= tot) return;
  int dst = (i < E) ? ei[E + i] : (i - E);
  atomicAdd(&cnt[dst], 1);
}

// single-block blocked scan: 1024 threads, each owns a contiguous chunk
__global__ __launch_bounds__(1024) void k_scan(const int* __restrict__ cnt,
                                               int* __restrict__ rowp, int n) {
  __shared__ int sm[1024];
  int tid = threadIdx.x;
  int CH = (n + 1023) >> 10;
  int b = tid * CH, e = b + CH;
  if (b > n) b = n;
  if (e > n) e = n;
  int s = 0;
  for (int i = b; i < e; ++i) s += cnt[i];
  sm[tid] = s;
  __syncthreads();
  for (int off = 1; off < 1024; off <<= 1) {
    int t = (tid >= off) ? sm[tid - off] : 0;
    __syncthreads();
    sm[tid] += t;
    __syncthreads();
  }
  int run = sm[tid] - s;  // exclusive prefix of this chunk
  for (int i = b; i < e; ++i) { rowp[i] = run; run += cnt[i]; }
  if (tid == 1023) rowp[n] = run;
}

__global__ __launch_bounds__(256) void k_copy(const int* __restrict__ a,
                                              int* __restrict__ b, int n) {
  int i = blockIdx.x * 256 + threadIdx.x;
  if (i < n) b[i] = a[i];
}

__global__ __launch_bounds__(256) void k_scatter(const int* __restrict__ ei,
                                                 int* __restrict__ cursor,
                                                 int* __restrict__ csr_src, int E, int N) {
  int i = blockIdx.x * 256 + threadIdx.x;
  int tot = E + N;
  if (i >= tot) return;
  int src, dst;
  if (i < E) { src = ei[i]; dst = ei[E + i]; }
  else       { src = i - E; dst = i - E; }
  int pos = atomicAdd(&cursor[dst], 1);
  csr_src[pos] = src;
}

// layer-1 GEMM: X [N,4] @ W [4,128]
__global__ __launch_bounds__(256) void k_gemm4(const float* __restrict__ X,
                                               const float* __restrict__ W,
                                               float* __restrict__ Hout, int N) {
  int idx = blockIdx.x * 256 + threadIdx.x;
  if (idx >= N * 128) return;
  int n = idx >> 7, j = idx & 127;
  float4 xv = *(const float4*)(X + n * 4);
  float h = xv.x * W[j] + xv.y * W[128 + j] + xv.z * W[256 + j] + xv.w * W[384 + j];
  Hout[idx] = h;
}

// GEMM: X [N,128] @ W [128,128] -> Hout [N,128]
__global__ __launch_bounds__(256) void k_gemm128(const float* __restrict__ X,
                                                 const float* __restrict__ W,
                                                 float* __restrict__ Hout, int N) {
  __shared__ float Ws[64 * 128];    // 32 KB
  __shared__ float Xs[64 * 68];     // 17 KB
  int tid = threadIdx.x;
  int base = blockIdx.x * 64;
  int ty = tid >> 4, tx = tid & 15;

  float acc[4][8];
#pragma unroll
  for (int r = 0; r < 4; ++r)
#pragma unroll
    for (int c = 0; c < 8; ++c) acc[r][c] = 0.f;

  for (int kk = 0; kk < 128; kk += 64) {
    __syncthreads();
    for (int i = tid * 4; i < 64 * 128; i += 1024) {
      *(float4*)(Ws + i) = *(const float4*)(W + kk * 128 + i);
    }
    for (int i = tid; i < 64 * 16; i += 256) {
      int node = i >> 4, k4 = (i & 15) << 2;
      int gn = base + node;
      float4 v;
      if (gn < N) v = *(const float4*)(X + gn * 128 + kk + k4);
      else        v = make_float4(0.f, 0.f, 0.f, 0.f);
      *(float4*)(Xs + node * 68 + k4) = v;
    }
    __syncthreads();

    for (int k = 0; k < 64; ++k) {
      float a0 = Xs[(ty * 4 + 0) * 68 + k];
      float a1 = Xs[(ty * 4 + 1) * 68 + k];
      float a2 = Xs[(ty * 4 + 2) * 68 + k];
      float a3 = Xs[(ty * 4 + 3) * 68 + k];
      float4 b0 = *(const float4*)(Ws + k * 128 + tx * 8);
      float4 b1 = *(const float4*)(Ws + k * 128 + tx * 8 + 4);
      acc[0][0] += a0 * b0.x; acc[0][1] += a0 * b0.y; acc[0][2] += a0 * b0.z; acc[0][3] += a0 * b0.w;
      acc[0][4] += a0 * b1.x; acc[0][5] += a0 * b1.y; acc[0][6] += a0 * b1.z; acc[0][7] += a0 * b1.w;
      acc[1][0] += a1 * b0.x; acc[1][1] += a1 * b0.y; acc[1][2] += a1 * b0.z; acc[1][3] += a1 * b0.w;
      acc[1][4] += a1 * b1.x; acc[1][5] += a1 * b1.y; acc[1][6] += a1 * b1.z; acc[1][7] += a1 * b1.w;
      acc[2][0] += a2 * b0.x; acc[2][1] += a2 * b0.y; acc[2][2] += a2 * b0.z; acc[2][3] += a2 * b0.w;
      acc[2][4] += a2 * b1.x; acc[2][5] += a2 * b1.y; acc[2][6] += a2 * b1.z; acc[2][7] += a2 * b1.w;
      acc[3][0] += a3 * b0.x; acc[3][1] += a3 * b0.y; acc[3][2] += a3 * b0.z; acc[3][3] += a3 * b0.w;
      acc[3][4] += a3 * b1.x; acc[3][5] += a3 * b1.y; acc[3][6] += a3 * b1.z; acc[3][7] += a3 * b1.w;
    }
  }

#pragma unroll
  for (int r = 0; r < 4; ++r) {
    int gn = base + ty * 4 + r;
    if (gn < N) {
      float4 o0 = make_float4(acc[r][0], acc[r][1], acc[r][2], acc[r][3]);
      float4 o1 = make_float4(acc[r][4], acc[r][5], acc[r][6], acc[r][7]);
      *(float4*)(Hout + gn * 128 + tx * 8) = o0;
      *(float4*)(Hout + gn * 128 + tx * 8 + 4) = o1;
    }
  }
}

// per-node attention logits: al_s = h . a_src, al_d = h . a_dst  (one wave/node)
__global__ __launch_bounds__(256) void k_al(const float* __restrict__ Hh,
                                            const float* __restrict__ asv,
                                            const float* __restrict__ adv,
                                            float* __restrict__ al_s,
                                            float* __restrict__ al_d, int N) {
  int wid = threadIdx.x >> 6, lane = threadIdx.x & 63;
  int node = blockIdx.x * 4 + wid;
  if (node >= N) return;
  float2 h = *(const float2*)(Hh + node * 128 + lane * 2);
  float2 s2 = *(const float2*)(asv + lane * 2);
  float2 d2 = *(const float2*)(adv + lane * 2);
  float ps = h.x * s2.x + h.y * s2.y;
  float pd = h.x * d2.x + h.y * d2.y;
  for (int off = 32; off; off >>= 1) {
    ps += __shfl_xor(ps, off);
    pd += __shfl_xor(pd, off);
  }
  if (lane == 0) { al_s[node] = ps; al_d[node] = pd; }
}

// per-dst softmax + aggregation. one wave per dst; per-edge scratch exw.
// Pass A: gather al_s, leaky-relu, store e -> exw, reduce max.
// Pass B: read exw, expf, store ex -> exw, reduce denom.
// Pass C: w = exw[j]*inv (uniform, sequential), gather Hh rows, unroll x4.
__global__ __launch_bounds__(256) void k_agg(const int* __restrict__ csr_src,
                                             const int* __restrict__ rowp,
                                             const float* __restrict__ al_s,
                                             const float* __restrict__ al_d,
                                             const float* __restrict__ Hh,
                                             const float* __restrict__ bias,
                                             float* __restrict__ exw,
                                             float* __restrict__ Yout, int N, int relu) {
  int wid = threadIdx.x >> 6, lane = threadIdx.x & 63;
  int dst = blockIdx.x * 4 + wid;
  if (dst >= N) return;
  int beg = rowp[dst], end = rowp[dst + 1];
  float ald = al_d[dst];

  float m = -INFINITY;
  for (int j = beg + lane; j < end; j += 64) {
    float e = al_s[csr_src[j]] + ald;
    e = (e > 0.f) ? e : 0.2f * e;
    exw[j] = e;
    m = fmaxf(m, e);
  }
  for (int off = 32; off; off >>= 1) m = fmaxf(m, __shfl_xor(m, off));

  float den = 0.f;
  for (int j = beg + lane; j < end; j += 64) {
    float ex = __expf(exw[j] - m);
    exw[j] = ex;
    den += ex;
  }
  for (int off = 32; off; off >>= 1) den += __shfl_xor(den, off);
  float inv = 1.0f / (den + 1e-16f);

  float2 acc = {0.f, 0.f};
  int j = beg;
  for (; j + 4 <= end; j += 4) {
    int s0 = csr_src[j], s1 = csr_src[j + 1], s2 = csr_src[j + 2], s3 = csr_src[j + 3];
    float w0 = exw[j] * inv, w1 = exw[j + 1] * inv;
    float w2 = exw[j + 2] * inv, w3 = exw[j + 3] * inv;
    float2 h0 = *(const float2*)(Hh + (size_t)s0 * 128 + lane * 2);
    float2 h1 = *(const float2*)(Hh + (size_t)s1 * 128 + lane * 2);
    float2 h2 = *(const float2*)(Hh + (size_t)s2 * 128 + lane * 2);
    float2 h3 = *(const float2*)(Hh + (size_t)s3 * 128 + lane * 2);
    acc.x += w0 * h0.x + w1 * h1.x + w2 * h2.x + w3 * h3.x;
    acc.y += w0 * h0.y + w1 * h1.y + w2 * h2.y + w3 * h3.y;
  }
  for (; j < end; ++j) {
    int s = csr_src[j];
    float w = exw[j] * inv;
    float2 hv = *(const float2*)(Hh + (size_t)s * 128 + lane * 2);
    acc.x += w * hv.x;
    acc.y += w * hv.y;
  }
  float2 bv = *(const float2*)(bias + lane * 2);
  float2 o = {acc.x + bv.x, acc.y + bv.y};
  if (relu) { o.x = fmaxf(o.x, 0.f); o.y = fmaxf(o.y, 0.f); }
  *(float2*)(Yout + dst * 128 + lane * 2) = o;
}

// run-length pooling over sorted batch
__global__ __launch_bounds__(256) void k_pool(const float* __restrict__ Hh,
                                              const int* __restrict__ batch,
                                              float* __restrict__ gsum,
                                              float* __restrict__ gcnt,
                                              int N, int nwaves) {
  int gw = (blockIdx.x * 256 + threadIdx.x) >> 6;
  int lane = threadIdx.x & 63;
  int chunk = (N + nwaves - 1) / nwaves;
  int beg = gw * chunk;
  int end = beg + chunk; if (end > N) end = N;
  if (beg >= end) return;

  int curg = batch[beg];
  float2 acc = {0.f, 0.f};
  int cnt = 0;
  for (int n = beg; n < end; ++n) {
    int g = batch[n];
    if (g != curg) {
      atomicAdd(&gsum[curg * 128 + lane * 2], acc.x);
      atomicAdd(&gsum[curg * 128 + lane * 2 + 1], acc.y);
      if (lane == 0) atomicAdd(&gcnt[curg], (float)cnt);
      acc.x = 0.f; acc.y = 0.f; cnt = 0; curg = g;
    }
    float2 h = *(const float2*)(Hh + (size_t)n * 128 + lane * 2);
    acc.x += h.x; acc.y += h.y; ++cnt;
  }
  atomicAdd(&gsum[curg * 128 + lane * 2], acc.x);
  atomicAdd(&gsum[curg * 128 + lane * 2 + 1], acc.y);
  if (lane == 0) atomicAdd(&gcnt[curg], (float)cnt);
}

__global__ __launch_bounds__(128) void k_final(const float* __restrict__ gsum,
                                               const float* __restrict__ gcnt,
                                               const float* __restrict__ Wlin,
                                               const float* __restrict__ blin,
                                               float* __restrict__ out) {
  int t = threadIdx.x;  // 128 threads: (g, c) pairs
  int g = t >> 1, c = t & 1;
  float inv = 1.0f / fmaxf(gcnt[g], 1.0f);
  float acc = blin[c];
  for (int k = 0; k < 128; ++k) acc += gsum[g * 128 + k] * inv * Wlin[k * 2 + c];
  out[g * 2 + c] = acc;
}

extern "C" void kernel_launch(void* const* d_in, const int* in_sizes, int n_in,
                              void* d_out, int out_size, void* d_ws, size_t ws_size,
                              hipStream_t stream) {
  const float* x    = (const float*)d_in[0];
  const int*   ei   = (const int*)d_in[1];
  const int*   batch= (const int*)d_in[2];
  const float* W1   = (const float*)d_in[3];
  const float* as1  = (const float*)d_in[4];
  const float* ad1  = (const float*)d_in[5];
  const float* b1   = (const float*)d_in[6];
  const float* W2   = (const float*)d_in[7];
  const float* as2  = (const float*)d_in[8];
  const float* ad2  = (const float*)d_in[9];
  const float* b2   = (const float*)d_in[10];
  const float* W3   = (const float*)d_in[11];
  const float* as3  = (const float*)d_in[12];
  const float* ad3  = (const float*)d_in[13];
  const float* b3   = (const float*)d_in[14];
  const float* Wlin = (const float*)d_in[15];
  const float* blin = (const float*)d_in[16];

  int N = in_sizes[0] / 4;
  int E = in_sizes[1] / 2;
  int ET = E + N;

  char* ws = (char*)d_ws;
  float* bufA = (float*)ws; ws += (size_t)N * 128 * 4;
  float* bufB = (float*)ws; ws += (size_t)N * 128 * 4;
  float* al_s = (float*)ws; ws += (size_t)N * 4;
  float* al_d = (float*)ws; ws += (size_t)N * 4;
  float* gsum = (float*)ws; ws += (size_t)64 * 128 * 4;
  float* gcnt = (float*)ws; ws += (size_t)64 * 4;
  int* rowp   = (int*)ws;   ws += (size_t)(N + 1) * 4;
  int* cursor = (int*)ws;   ws += (size_t)N * 4;
  int* csr    = (int*)ws;   ws += (size_t)ET * 4;
  float* exw  = (float*)ws; ws += (size_t)ET * 4;

  hipMemsetAsync(cursor, 0, (size_t)N * 4, stream);
  hipMemsetAsync(gsum, 0, (size_t)(64 * 128 + 64) * 4, stream);  // gsum + gcnt

  int eb = (ET + 255) / 256;
  k_count  <<<eb, 256, 0, stream>>>(ei, cursor, E, N);
  k_scan   <<<1, 1024, 0, stream>>>(cursor, rowp, N);
  k_copy   <<<(N + 255) / 256, 256, 0, stream>>>(rowp, cursor, N);
  k_scatter<<<eb, 256, 0, stream>>>(ei, cursor, csr, E, N);

  int nb4 = (N + 3) / 4;
  // layer 1
  k_gemm4<<<(N * 128 + 255) / 256, 256, 0, stream>>>(x, W1, bufA, N);
  k_al   <<<nb4, 256, 0, stream>>>(bufA, as1, ad1, al_s, al_d, N);
  k_agg  <<<nb4, 256, 0, stream>>>(csr, rowp, al_s, al_d, bufA, b1, exw, bufB, N, 1);
  // layer 2
  k_gemm128<<<(N + 63) / 64, 256, 0, stream>>>(bufB, W2, bufA, N);
  k_al     <<<nb4, 256, 0, stream>>>(bufA, as2, ad2, al_s, al_d, N);
  k_agg    <<<nb4, 256, 0, stream>>>(csr, rowp, al_s, al_d, bufA, b2, exw, bufB, N, 1);
  // layer 3
  k_gemm128<<<(N + 63) / 64, 256, 0, stream>>>(bufB, W3, bufA, N);
  k_al     <<<nb4, 256, 0, stream>>>(bufA, as3, ad3, al_s, al_d, N);
  k_agg    <<<nb4, 256, 0, stream>>>(csr, rowp, al_s, al_d, bufA, b3, exw, bufB, N, 0);

  // global mean pool + linear head (256 blocks x 4 waves = 1024 waves)
  k_pool <<<256, 256, 0, stream>>>(bufB, batch, gsum, gcnt, N, 1024);
  k_final<<<1, 128, 0, stream>>>(gsum, gcnt, Wlin, blin, (float*)d_out);
}

// Round 4
// 524.247 us; speedup vs baseline: 1.9973x; 1.1319x over previous
//
#include <hip/hip_runtime.h>
#include <math.h>

// ---------------------------------------------------------------------------
// GAT 3-layer net. CSR by dst built once per call; per-layer:
//   gemm (h = X@W), al (al_s/al_d = h@a), agg (per-dst wave softmax+gather).
// R1: k_pool run-length accumulation (batch sorted) — 362us -> ~5us.
// R2: k_agg 3-pass with per-edge scratch (scratch e/exp, unroll x4 gather).
// R3: hierarchical 3-kernel scan (single-block scan was 76us at 0.15% occ,
//     uncoalesced per-thread chunks; now coalesced int4 + 49-block scan).
// ---------------------------------------------------------------------------

__global__ __launch_bounds__(256) void k_count(const int* __restrict__ ei,
                                               int* __restrict__ cnt, int E, int N) {
  int i = blockIdx.x * 256 + threadIdx.x;
  int tot = E + N;
  if (i >= tot) return;
  int dst = (i < E) ? ei[E + i] : (i - E);
  atomicAdd(&cnt[dst], 1);
}

// hierarchical scan, stage 1: 1024 elems/block (256 thr x int4).
// writes block-local exclusive scan into rowp and block total into bsum.
__global__ __launch_bounds__(256) void k_scan1(const int* __restrict__ cnt,
                                               int* __restrict__ rowp,
                                               int* __restrict__ bsum, int n) {
  __shared__ int sm[256];
  int tid = threadIdx.x;
  int base = blockIdx.x * 1024 + tid * 4;
  int4 v = {0, 0, 0, 0};
  if (base + 3 < n) v = *(const int4*)(cnt + base);
  else {
    if (base + 0 < n) v.x = cnt[base + 0];
    if (base + 1 < n) v.y = cnt[base + 1];
    if (base + 2 < n) v.z = cnt[base + 2];
    if (base + 3 < n) v.w = cnt[base + 3];
  }
  int s = v.x + v.y + v.z + v.w;
  sm[tid] = s;
  __syncthreads();
  for (int off = 1; off < 256; off <<= 1) {
    int t = (tid >= off) ? sm[tid - off] : 0;
    __syncthreads();
    sm[tid] += t;
    __syncthreads();
  }
  int pre = sm[tid] - s;  // exclusive prefix within block
  int r0 = pre, r1 = pre + v.x, r2 = r1 + v.y, r3 = r2 + v.z;
  if (base + 3 < n) { int4 o = {r0, r1, r2, r3}; *(int4*)(rowp + base) = o; }
  else {
    if (base + 0 < n) rowp[base + 0] = r0;
    if (base + 1 < n) rowp[base + 1] = r1;
    if (base + 2 < n) rowp[base + 2] = r2;
    if (base + 3 < n) rowp[base + 3] = r3;
  }
  if (tid == 255) bsum[blockIdx.x] = sm[255];
}

// stage 2: single block exclusive-scans nb (<=256) block sums in place
__global__ __launch_bounds__(256) void k_scan2(int* __restrict__ bsum, int nb) {
  __shared__ int sm[256];
  int tid = threadIdx.x;
  int v = (tid < nb) ? bsum[tid] : 0;
  sm[tid] = v;
  __syncthreads();
  for (int off = 1; off < 256; off <<= 1) {
    int t = (tid >= off) ? sm[tid - off] : 0;
    __syncthreads();
    sm[tid] += t;
    __syncthreads();
  }
  if (tid < nb) bsum[tid] = sm[tid] - v;
}

// stage 3: add block offsets; write rowp[n] = total (known statically)
__global__ __launch_bounds__(256) void k_scan3(int* __restrict__ rowp,
                                               const int* __restrict__ bsum,
                                               int n, int total) {
  int tid = threadIdx.x;
  int base = blockIdx.x * 1024 + tid * 4;
  int off = bsum[blockIdx.x];
  if (base + 3 < n) {
    int4 v = *(int4*)(rowp + base);
    v.x += off; v.y += off; v.z += off; v.w += off;
    *(int4*)(rowp + base) = v;
  } else {
    for (int i = 0; i < 4; ++i)
      if (base + i < n) rowp[base + i] += off;
  }
  if (blockIdx.x == 0 && tid == 0) rowp[n] = total;
}

__global__ __launch_bounds__(256) void k_copy(const int* __restrict__ a,
                                              int* __restrict__ b, int n) {
  int i = blockIdx.x * 256 + threadIdx.x;
  if (i < n) b[i] = a[i];
}

__global__ __launch_bounds__(256) void k_scatter(const int* __restrict__ ei,
                                                 int* __restrict__ cursor,
                                                 int* __restrict__ csr_src, int E, int N) {
  int i = blockIdx.x * 256 + threadIdx.x;
  int tot = E + N;
  if (i >= tot) return;
  int src, dst;
  if (i < E) { src = ei[i]; dst = ei[E + i]; }
  else       { src = i - E; dst = i - E; }
  int pos = atomicAdd(&cursor[dst], 1);
  csr_src[pos] = src;
}

// layer-1 GEMM: X [N,4] @ W [4,128]
__global__ __launch_bounds__(256) void k_gemm4(const float* __restrict__ X,
                                               const float* __restrict__ W,
                                               float* __restrict__ Hout, int N) {
  int idx = blockIdx.x * 256 + threadIdx.x;
  if (idx >= N * 128) return;
  int n = idx >> 7, j = idx & 127;
  float4 xv = *(const float4*)(X + n * 4);
  float h = xv.x * W[j] + xv.y * W[128 + j] + xv.z * W[256 + j] + xv.w * W[384 + j];
  Hout[idx] = h;
}

// GEMM: X [N,128] @ W [128,128] -> Hout [N,128]
__global__ __launch_bounds__(256) void k_gemm128(const float* __restrict__ X,
                                                 const float* __restrict__ W,
                                                 float* __restrict__ Hout, int N) {
  __shared__ float Ws[64 * 128];    // 32 KB
  __shared__ float Xs[64 * 68];     // 17 KB
  int tid = threadIdx.x;
  int base = blockIdx.x * 64;
  int ty = tid >> 4, tx = tid & 15;

  float acc[4][8];
#pragma unroll
  for (int r = 0; r < 4; ++r)
#pragma unroll
    for (int c = 0; c < 8; ++c) acc[r][c] = 0.f;

  for (int kk = 0; kk < 128; kk += 64) {
    __syncthreads();
    for (int i = tid * 4; i < 64 * 128; i += 1024) {
      *(float4*)(Ws + i) = *(const float4*)(W + kk * 128 + i);
    }
    for (int i = tid; i < 64 * 16; i += 256) {
      int node = i >> 4, k4 = (i & 15) << 2;
      int gn = base + node;
      float4 v;
      if (gn < N) v = *(const float4*)(X + gn * 128 + kk + k4);
      else        v = make_float4(0.f, 0.f, 0.f, 0.f);
      *(float4*)(Xs + node * 68 + k4) = v;
    }
    __syncthreads();

    for (int k = 0; k < 64; ++k) {
      float a0 = Xs[(ty * 4 + 0) * 68 + k];
      float a1 = Xs[(ty * 4 + 1) * 68 + k];
      float a2 = Xs[(ty * 4 + 2) * 68 + k];
      float a3 = Xs[(ty * 4 + 3) * 68 + k];
      float4 b0 = *(const float4*)(Ws + k * 128 + tx * 8);
      float4 b1 = *(const float4*)(Ws + k * 128 + tx * 8 + 4);
      acc[0][0] += a0 * b0.x; acc[0][1] += a0 * b0.y; acc[0][2] += a0 * b0.z; acc[0][3] += a0 * b0.w;
      acc[0][4] += a0 * b1.x; acc[0][5] += a0 * b1.y; acc[0][6] += a0 * b1.z; acc[0][7] += a0 * b1.w;
      acc[1][0] += a1 * b0.x; acc[1][1] += a1 * b0.y; acc[1][2] += a1 * b0.z; acc[1][3] += a1 * b0.w;
      acc[1][4] += a1 * b1.x; acc[1][5] += a1 * b1.y; acc[1][6] += a1 * b1.z; acc[1][7] += a1 * b1.w;
      acc[2][0] += a2 * b0.x; acc[2][1] += a2 * b0.y; acc[2][2] += a2 * b0.z; acc[2][3] += a2 * b0.w;
      acc[2][4] += a2 * b1.x; acc[2][5] += a2 * b1.y; acc[2][6] += a2 * b1.z; acc[2][7] += a2 * b1.w;
      acc[3][0] += a3 * b0.x; acc[3][1] += a3 * b0.y; acc[3][2] += a3 * b0.z; acc[3][3] += a3 * b0.w;
      acc[3][4] += a3 * b1.x; acc[3][5] += a3 * b1.y; acc[3][6] += a3 * b1.z; acc[3][7] += a3 * b1.w;
    }
  }

#pragma unroll
  for (int r = 0; r < 4; ++r) {
    int gn = base + ty * 4 + r;
    if (gn < N) {
      float4 o0 = make_float4(acc[r][0], acc[r][1], acc[r][2], acc[r][3]);
      float4 o1 = make_float4(acc[r][4], acc[r][5], acc[r][6], acc[r][7]);
      *(float4*)(Hout + gn * 128 + tx * 8) = o0;
      *(float4*)(Hout + gn * 128 + tx * 8 + 4) = o1;
    }
  }
}

// per-node attention logits: al_s = h . a_src, al_d = h . a_dst  (one wave/node)
__global__ __launch_bounds__(256) void k_al(const float* __restrict__ Hh,
                                            const float* __restrict__ asv,
                                            const float* __restrict__ adv,
                                            float* __restrict__ al_s,
                                            float* __restrict__ al_d, int N) {
  int wid = threadIdx.x >> 6, lane = threadIdx.x & 63;
  int node = blockIdx.x * 4 + wid;
  if (node >= N) return;
  float2 h = *(const float2*)(Hh + node * 128 + lane * 2);
  float2 s2 = *(const float2*)(asv + lane * 2);
  float2 d2 = *(const float2*)(adv + lane * 2);
  float ps = h.x * s2.x + h.y * s2.y;
  float pd = h.x * d2.x + h.y * d2.y;
  for (int off = 32; off; off >>= 1) {
    ps += __shfl_xor(ps, off);
    pd += __shfl_xor(pd, off);
  }
  if (lane == 0) { al_s[node] = ps; al_d[node] = pd; }
}

// per-dst softmax + aggregation. one wave per dst; per-edge scratch exw.
__global__ __launch_bounds__(256) void k_agg(const int* __restrict__ csr_src,
                                             const int* __restrict__ rowp,
                                             const float* __restrict__ al_s,
                                             const float* __restrict__ al_d,
                                             const float* __restrict__ Hh,
                                             const float* __restrict__ bias,
                                             float* __restrict__ exw,
                                             float* __restrict__ Yout, int N, int relu) {
  int wid = threadIdx.x >> 6, lane = threadIdx.x & 63;
  int dst = blockIdx.x * 4 + wid;
  if (dst >= N) return;
  int beg = rowp[dst], end = rowp[dst + 1];
  float ald = al_d[dst];

  float m = -INFINITY;
  for (int j = beg + lane; j < end; j += 64) {
    float e = al_s[csr_src[j]] + ald;
    e = (e > 0.f) ? e : 0.2f * e;
    exw[j] = e;
    m = fmaxf(m, e);
  }
  for (int off = 32; off; off >>= 1) m = fmaxf(m, __shfl_xor(m, off));

  float den = 0.f;
  for (int j = beg + lane; j < end; j += 64) {
    float ex = __expf(exw[j] - m);
    exw[j] = ex;
    den += ex;
  }
  for (int off = 32; off; off >>= 1) den += __shfl_xor(den, off);
  float inv = 1.0f / (den + 1e-16f);

  float2 acc = {0.f, 0.f};
  int j = beg;
  for (; j + 4 <= end; j += 4) {
    int s0 = csr_src[j], s1 = csr_src[j + 1], s2 = csr_src[j + 2], s3 = csr_src[j + 3];
    float w0 = exw[j] * inv, w1 = exw[j + 1] * inv;
    float w2 = exw[j + 2] * inv, w3 = exw[j + 3] * inv;
    float2 h0 = *(const float2*)(Hh + (size_t)s0 * 128 + lane * 2);
    float2 h1 = *(const float2*)(Hh + (size_t)s1 * 128 + lane * 2);
    float2 h2 = *(const float2*)(Hh + (size_t)s2 * 128 + lane * 2);
    float2 h3 = *(const float2*)(Hh + (size_t)s3 * 128 + lane * 2);
    acc.x += w0 * h0.x + w1 * h1.x + w2 * h2.x + w3 * h3.x;
    acc.y += w0 * h0.y + w1 * h1.y + w2 * h2.y + w3 * h3.y;
  }
  for (; j < end; ++j) {
    int s = csr_src[j];
    float w = exw[j] * inv;
    float2 hv = *(const float2*)(Hh + (size_t)s * 128 + lane * 2);
    acc.x += w * hv.x;
    acc.y += w * hv.y;
  }
  float2 bv = *(const float2*)(bias + lane * 2);
  float2 o = {acc.x + bv.x, acc.y + bv.y};
  if (relu) { o.x = fmaxf(o.x, 0.f); o.y = fmaxf(o.y, 0.f); }
  *(float2*)(Yout + dst * 128 + lane * 2) = o;
}

// run-length pooling over sorted batch
__global__ __launch_bounds__(256) void k_pool(const float* __restrict__ Hh,
                                              const int* __restrict__ batch,
                                              float* __restrict__ gsum,
                                              float* __restrict__ gcnt,
                                              int N, int nwaves) {
  int gw = (blockIdx.x * 256 + threadIdx.x) >> 6;
  int lane = threadIdx.x & 63;
  int chunk = (N + nwaves - 1) / nwaves;
  int beg = gw * chunk;
  int end = beg + chunk; if (end > N) end = N;
  if (beg >= end) return;

  int curg = batch[beg];
  float2 acc = {0.f, 0.f};
  int cnt = 0;
  for (int n = beg; n < end; ++n) {
    int g = batch[n];
    if (g != curg) {
      atomicAdd(&gsum[curg * 128 + lane * 2], acc.x);
      atomicAdd(&gsum[curg * 128 + lane * 2 + 1], acc.y);
      if (lane == 0) atomicAdd(&gcnt[curg], (float)cnt);
      acc.x = 0.f; acc.y = 0.f; cnt = 0; curg = g;
    }
    float2 h = *(const float2*)(Hh + (size_t)n * 128 + lane * 2);
    acc.x += h.x; acc.y += h.y; ++cnt;
  }
  atomicAdd(&gsum[curg * 128 + lane * 2], acc.x);
  atomicAdd(&gsum[curg * 128 + lane * 2 + 1], acc.y);
  if (lane == 0) atomicAdd(&gcnt[curg], (float)cnt);
}

__global__ __launch_bounds__(128) void k_final(const float* __restrict__ gsum,
                                               const float* __restrict__ gcnt,
                                               const float* __restrict__ Wlin,
                                               const float* __restrict__ blin,
                                               float* __restrict__ out) {
  int t = threadIdx.x;  // 128 threads: (g, c) pairs
  int g = t >> 1, c = t & 1;
  float inv = 1.0f / fmaxf(gcnt[g], 1.0f);
  float acc = blin[c];
  for (int k = 0; k < 128; ++k) acc += gsum[g * 128 + k] * inv * Wlin[k * 2 + c];
  out[g * 2 + c] = acc;
}

extern "C" void kernel_launch(void* const* d_in, const int* in_sizes, int n_in,
                              void* d_out, int out_size, void* d_ws, size_t ws_size,
                              hipStream_t stream) {
  const float* x    = (const float*)d_in[0];
  const int*   ei   = (const int*)d_in[1];
  const int*   batch= (const int*)d_in[2];
  const float* W1   = (const float*)d_in[3];
  const float* as1  = (const float*)d_in[4];
  const float* ad1  = (const float*)d_in[5];
  const float* b1   = (const float*)d_in[6];
  const float* W2   = (const float*)d_in[7];
  const float* as2  = (const float*)d_in[8];
  const float* ad2  = (const float*)d_in[9];
  const float* b2   = (const float*)d_in[10];
  const float* W3   = (const float*)d_in[11];
  const float* as3  = (const float*)d_in[12];
  const float* ad3  = (const float*)d_in[13];
  const float* b3   = (const float*)d_in[14];
  const float* Wlin = (const float*)d_in[15];
  const float* blin = (const float*)d_in[16];

  int N = in_sizes[0] / 4;
  int E = in_sizes[1] / 2;
  int ET = E + N;

  char* ws = (char*)d_ws;
  float* bufA = (float*)ws; ws += (size_t)N * 128 * 4;
  float* bufB = (float*)ws; ws += (size_t)N * 128 * 4;
  float* al_s = (float*)ws; ws += (size_t)N * 4;
  float* al_d = (float*)ws; ws += (size_t)N * 4;
  float* gsum = (float*)ws; ws += (size_t)64 * 128 * 4;
  float* gcnt = (float*)ws; ws += (size_t)64 * 4;
  int* rowp   = (int*)ws;   ws += (size_t)(N + 1) * 4;
  int* cursor = (int*)ws;   ws += (size_t)N * 4;
  int* csr    = (int*)ws;   ws += (size_t)ET * 4;
  float* exw  = (float*)ws; ws += (size_t)ET * 4;
  int* bsum   = (int*)ws;   ws += (size_t)256 * 4;

  hipMemsetAsync(cursor, 0, (size_t)N * 4, stream);
  hipMemsetAsync(gsum, 0, (size_t)(64 * 128 + 64) * 4, stream);  // gsum + gcnt

  int eb = (ET + 255) / 256;
  int nsb = (N + 1023) / 1024;  // scan blocks (<=256)
  k_count  <<<eb, 256, 0, stream>>>(ei, cursor, E, N);
  k_scan1  <<<nsb, 256, 0, stream>>>(cursor, rowp, bsum, N);
  k_scan2  <<<1, 256, 0, stream>>>(bsum, nsb);
  k_scan3  <<<nsb, 256, 0, stream>>>(rowp, bsum, N, ET);
  k_copy   <<<(N + 255) / 256, 256, 0, stream>>>(rowp, cursor, N);
  k_scatter<<<eb, 256, 0, stream>>>(ei, cursor, csr, E, N);

  int nb4 = (N + 3) / 4;
  // layer 1
  k_gemm4<<<(N * 128 + 255) / 256, 256, 0, stream>>>(x, W1, bufA, N);
  k_al   <<<nb4, 256, 0, stream>>>(bufA, as1, ad1, al_s, al_d, N);
  k_agg  <<<nb4, 256, 0, stream>>>(csr, rowp, al_s, al_d, bufA, b1, exw, bufB, N, 1);
  // layer 2
  k_gemm128<<<(N + 63) / 64, 256, 0, stream>>>(bufB, W2, bufA, N);
  k_al     <<<nb4, 256, 0, stream>>>(bufA, as2, ad2, al_s, al_d, N);
  k_agg    <<<nb4, 256, 0, stream>>>(csr, rowp, al_s, al_d, bufA, b2, exw, bufB, N, 1);
  // layer 3
  k_gemm128<<<(N + 63) / 64, 256, 0, stream>>>(bufB, W3, bufA, N);
  k_al     <<<nb4, 256, 0, stream>>>(bufA, as3, ad3, al_s, al_d, N);
  k_agg    <<<nb4, 256, 0, stream>>>(csr, rowp, al_s, al_d, bufA, b3, exw, bufB, N, 0);

  // global mean pool + linear head (256 blocks x 4 waves = 1024 waves)
  k_pool <<<256, 256, 0, stream>>>(bufB, batch, gsum, gcnt, N, 1024);
  k_final<<<1, 128, 0, stream>>>(gsum, gcnt, Wlin, blin, (float*)d_out);
}

// Round 5
// 484.534 us; speedup vs baseline: 2.1610x; 1.0820x over previous
//
#include <hip/hip_runtime.h>
#include <math.h>

// ---------------------------------------------------------------------------
// GAT 3-layer net. CSR by dst built once per call; per-layer:
//   gemm+al fused (h = X@W, al_s/al_d epilogue), agg (per-dst softmax+gather).
// R1: k_pool run-length accumulation (batch sorted) — 362us -> ~5us.
// R2: k_agg 3-pass with per-edge scratch (scratch e/exp).
// R3: hierarchical 3-kernel coalesced scan (was 76us single-block).
// R4: k_agg pass C quarter-wave-per-edge (float4x2 row gather, 8-edge
//     unroll => 2x in-flight lines, half the load instrs); k_al fused into
//     gemm epilogues; k_copy folded into k_scan3.
// ---------------------------------------------------------------------------

__global__ __launch_bounds__(256) void k_count(const int* __restrict__ ei,
                                               int* __restrict__ cnt, int E, int N) {
  int i = blockIdx.x * 256 + threadIdx.x;
  int tot = E + N;
  if (i >= tot) return;
  int dst = (i < E) ? ei[E + i] : (i - E);
  atomicAdd(&cnt[dst], 1);
}

// hierarchical scan, stage 1: 1024 elems/block (256 thr x int4).
__global__ __launch_bounds__(256) void k_scan1(const int* __restrict__ cnt,
                                               int* __restrict__ rowp,
                                               int* __restrict__ bsum, int n) {
  __shared__ int sm[256];
  int tid = threadIdx.x;
  int base = blockIdx.x * 1024 + tid * 4;
  int4 v = {0, 0, 0, 0};
  if (base + 3 < n) v = *(const int4*)(cnt + base);
  else {
    if (base + 0 < n) v.x = cnt[base + 0];
    if (base + 1 < n) v.y = cnt[base + 1];
    if (base + 2 < n) v.z = cnt[base + 2];
    if (base + 3 < n) v.w = cnt[base + 3];
  }
  int s = v.x + v.y + v.z + v.w;
  sm[tid] = s;
  __syncthreads();
  for (int off = 1; off < 256; off <<= 1) {
    int t = (tid >= off) ? sm[tid - off] : 0;
    __syncthreads();
    sm[tid] += t;
    __syncthreads();
  }
  int pre = sm[tid] - s;
  int r0 = pre, r1 = pre + v.x, r2 = r1 + v.y, r3 = r2 + v.z;
  if (base + 3 < n) { int4 o = {r0, r1, r2, r3}; *(int4*)(rowp + base) = o; }
  else {
    if (base + 0 < n) rowp[base + 0] = r0;
    if (base + 1 < n) rowp[base + 1] = r1;
    if (base + 2 < n) rowp[base + 2] = r2;
    if (base + 3 < n) rowp[base + 3] = r3;
  }
  if (tid == 255) bsum[blockIdx.x] = sm[255];
}

// stage 2: single block exclusive-scans nb (<=256) block sums in place
__global__ __launch_bounds__(256) void k_scan2(int* __restrict__ bsum, int nb) {
  __shared__ int sm[256];
  int tid = threadIdx.x;
  int v = (tid < nb) ? bsum[tid] : 0;
  sm[tid] = v;
  __syncthreads();
  for (int off = 1; off < 256; off <<= 1) {
    int t = (tid >= off) ? sm[tid - off] : 0;
    __syncthreads();
    sm[tid] += t;
    __syncthreads();
  }
  if (tid < nb) bsum[tid] = sm[tid] - v;
}

// stage 3: add block offsets; write final rowp AND cursor copy; rowp[n]=total
__global__ __launch_bounds__(256) void k_scan3(int* __restrict__ rowp,
                                               int* __restrict__ cursor,
                                               const int* __restrict__ bsum,
                                               int n, int total) {
  int tid = threadIdx.x;
  int base = blockIdx.x * 1024 + tid * 4;
  int off = bsum[blockIdx.x];
  if (base + 3 < n) {
    int4 v = *(int4*)(rowp + base);
    v.x += off; v.y += off; v.z += off; v.w += off;
    *(int4*)(rowp + base) = v;
    *(int4*)(cursor + base) = v;
  } else {
    for (int i = 0; i < 4; ++i)
      if (base + i < n) { int t = rowp[base + i] + off; rowp[base + i] = t; cursor[base + i] = t; }
  }
  if (blockIdx.x == 0 && tid == 0) rowp[n] = total;
}

__global__ __launch_bounds__(256) void k_scatter(const int* __restrict__ ei,
                                                 int* __restrict__ cursor,
                                                 int* __restrict__ csr_src, int E, int N) {
  int i = blockIdx.x * 256 + threadIdx.x;
  int tot = E + N;
  if (i >= tot) return;
  int src, dst;
  if (i < E) { src = ei[i]; dst = ei[E + i]; }
  else       { src = i - E; dst = i - E; }
  int pos = atomicAdd(&cursor[dst], 1);
  csr_src[pos] = src;
}

// layer-1 GEMM fused with al: one wave per node, lane owns 2 features.
__global__ __launch_bounds__(256) void k_gemm4al(const float* __restrict__ X,
                                                 const float* __restrict__ W,
                                                 const float* __restrict__ asv,
                                                 const float* __restrict__ adv,
                                                 float* __restrict__ Hout,
                                                 float* __restrict__ al_s,
                                                 float* __restrict__ al_d, int N) {
  int wid = threadIdx.x >> 6, lane = threadIdx.x & 63;
  int node = blockIdx.x * 4 + wid;
  if (node >= N) return;
  float4 xv = *(const float4*)(X + node * 4);
  int f = lane * 2;
  float2 w0 = *(const float2*)(W + f);
  float2 w1 = *(const float2*)(W + 128 + f);
  float2 w2 = *(const float2*)(W + 256 + f);
  float2 w3 = *(const float2*)(W + 384 + f);
  float h0 = xv.x * w0.x + xv.y * w1.x + xv.z * w2.x + xv.w * w3.x;
  float h1 = xv.x * w0.y + xv.y * w1.y + xv.z * w2.y + xv.w * w3.y;
  float2 hv = {h0, h1};
  *(float2*)(Hout + node * 128 + f) = hv;
  float2 s2 = *(const float2*)(asv + f);
  float2 d2 = *(const float2*)(adv + f);
  float ps = h0 * s2.x + h1 * s2.y;
  float pd = h0 * d2.x + h1 * d2.y;
  for (int off = 32; off; off >>= 1) {
    ps += __shfl_xor(ps, off);
    pd += __shfl_xor(pd, off);
  }
  if (lane == 0) { al_s[node] = ps; al_d[node] = pd; }
}

// GEMM: X [N,128] @ W [128,128] -> Hout [N,128], fused al epilogue.
__global__ __launch_bounds__(256) void k_gemm128al(const float* __restrict__ X,
                                                   const float* __restrict__ W,
                                                   const float* __restrict__ asv,
                                                   const float* __restrict__ adv,
                                                   float* __restrict__ Hout,
                                                   float* __restrict__ al_s,
                                                   float* __restrict__ al_d, int N) {
  __shared__ float Ws[64 * 128];    // 32 KB
  __shared__ float Xs[64 * 68];     // 17 KB
  int tid = threadIdx.x;
  int base = blockIdx.x * 64;
  int ty = tid >> 4, tx = tid & 15;

  float acc[4][8];
#pragma unroll
  for (int r = 0; r < 4; ++r)
#pragma unroll
    for (int c = 0; c < 8; ++c) acc[r][c] = 0.f;

  for (int kk = 0; kk < 128; kk += 64) {
    __syncthreads();
    for (int i = tid * 4; i < 64 * 128; i += 1024) {
      *(float4*)(Ws + i) = *(const float4*)(W + kk * 128 + i);
    }
    for (int i = tid; i < 64 * 16; i += 256) {
      int node = i >> 4, k4 = (i & 15) << 2;
      int gn = base + node;
      float4 v;
      if (gn < N) v = *(const float4*)(X + gn * 128 + kk + k4);
      else        v = make_float4(0.f, 0.f, 0.f, 0.f);
      *(float4*)(Xs + node * 68 + k4) = v;
    }
    __syncthreads();

    for (int k = 0; k < 64; ++k) {
      float a0 = Xs[(ty * 4 + 0) * 68 + k];
      float a1 = Xs[(ty * 4 + 1) * 68 + k];
      float a2 = Xs[(ty * 4 + 2) * 68 + k];
      float a3 = Xs[(ty * 4 + 3) * 68 + k];
      float4 b0 = *(const float4*)(Ws + k * 128 + tx * 8);
      float4 b1 = *(const float4*)(Ws + k * 128 + tx * 8 + 4);
      acc[0][0] += a0 * b0.x; acc[0][1] += a0 * b0.y; acc[0][2] += a0 * b0.z; acc[0][3] += a0 * b0.w;
      acc[0][4] += a0 * b1.x; acc[0][5] += a0 * b1.y; acc[0][6] += a0 * b1.z; acc[0][7] += a0 * b1.w;
      acc[1][0] += a1 * b0.x; acc[1][1] += a1 * b0.y; acc[1][2] += a1 * b0.z; acc[1][3] += a1 * b0.w;
      acc[1][4] += a1 * b1.x; acc[1][5] += a1 * b1.y; acc[1][6] += a1 * b1.z; acc[1][7] += a1 * b1.w;
      acc[2][0] += a2 * b0.x; acc[2][1] += a2 * b0.y; acc[2][2] += a2 * b0.z; acc[2][3] += a2 * b0.w;
      acc[2][4] += a2 * b1.x; acc[2][5] += a2 * b1.y; acc[2][6] += a2 * b1.z; acc[2][7] += a2 * b1.w;
      acc[3][0] += a3 * b0.x; acc[3][1] += a3 * b0.y; acc[3][2] += a3 * b0.z; acc[3][3] += a3 * b0.w;
      acc[3][4] += a3 * b1.x; acc[3][5] += a3 * b1.y; acc[3][6] += a3 * b1.z; acc[3][7] += a3 * b1.w;
    }
  }

  // epilogue: store h and fused al reduction (tx-group of 16 lanes per row)
  float4 as0 = *(const float4*)(asv + tx * 8);
  float4 as1 = *(const float4*)(asv + tx * 8 + 4);
  float4 ad0 = *(const float4*)(adv + tx * 8);
  float4 ad1 = *(const float4*)(adv + tx * 8 + 4);
#pragma unroll
  for (int r = 0; r < 4; ++r) {
    int gn = base + ty * 4 + r;
    float ps = acc[r][0] * as0.x + acc[r][1] * as0.y + acc[r][2] * as0.z + acc[r][3] * as0.w
             + acc[r][4] * as1.x + acc[r][5] * as1.y + acc[r][6] * as1.z + acc[r][7] * as1.w;
    float pd = acc[r][0] * ad0.x + acc[r][1] * ad0.y + acc[r][2] * ad0.z + acc[r][3] * ad0.w
             + acc[r][4] * ad1.x + acc[r][5] * ad1.y + acc[r][6] * ad1.z + acc[r][7] * ad1.w;
    for (int off = 1; off < 16; off <<= 1) {
      ps += __shfl_xor(ps, off);
      pd += __shfl_xor(pd, off);
    }
    if (gn < N) {
      float4 o0 = make_float4(acc[r][0], acc[r][1], acc[r][2], acc[r][3]);
      float4 o1 = make_float4(acc[r][4], acc[r][5], acc[r][6], acc[r][7]);
      *(float4*)(Hout + gn * 128 + tx * 8) = o0;
      *(float4*)(Hout + gn * 128 + tx * 8 + 4) = o1;
      if (tx == 0) { al_s[gn] = ps; al_d[gn] = pd; }
    }
  }
}

// per-dst softmax + aggregation. one wave per dst; per-edge scratch exw.
// Pass A: gather al_s, leaky-relu, store e; reduce max (lane-strided).
// Pass B: exp, store, reduce denom (lane-strided).
// Pass C: quarter-wave per edge: 16 lanes own the 512B row (float4 x2),
//         4 edges/wave-step, 8-edge unroll; cross-quarter shfl reduce.
__global__ __launch_bounds__(256) void k_agg(const int* __restrict__ csr_src,
                                             const int* __restrict__ rowp,
                                             const float* __restrict__ al_s,
                                             const float* __restrict__ al_d,
                                             const float* __restrict__ Hh,
                                             const float* __restrict__ bias,
                                             float* __restrict__ exw,
                                             float* __restrict__ Yout, int N, int relu) {
  int wid = threadIdx.x >> 6, lane = threadIdx.x & 63;
  int dst = blockIdx.x * 4 + wid;
  if (dst >= N) return;
  int beg = rowp[dst], end = rowp[dst + 1];
  float ald = al_d[dst];

  float m = -INFINITY;
  for (int j = beg + lane; j < end; j += 64) {
    float e = al_s[csr_src[j]] + ald;
    e = (e > 0.f) ? e : 0.2f * e;
    exw[j] = e;
    m = fmaxf(m, e);
  }
  for (int off = 32; off; off >>= 1) m = fmaxf(m, __shfl_xor(m, off));

  float den = 0.f;
  for (int j = beg + lane; j < end; j += 64) {
    float ex = __expf(exw[j] - m);
    exw[j] = ex;
    den += ex;
  }
  for (int off = 32; off; off >>= 1) den += __shfl_xor(den, off);
  float inv = 1.0f / (den + 1e-16f);

  int q = lane >> 4;       // quarter = edge offset within 4-edge group
  int l = lane & 15;       // feature lane: owns feats [l*8, l*8+8)
  const float* Hl = Hh + l * 8;
  float acc[8];
#pragma unroll
  for (int c = 0; c < 8; ++c) acc[c] = 0.f;

  int j = beg;
  for (; j + 8 <= end; j += 8) {
    int sA = csr_src[j + q];
    int sB = csr_src[j + 4 + q];
    float wA = exw[j + q] * inv;
    float wB = exw[j + 4 + q] * inv;
    const float* rA = Hl + (size_t)sA * 128;
    const float* rB = Hl + (size_t)sB * 128;
    float4 a0 = *(const float4*)(rA);
    float4 a1 = *(const float4*)(rA + 4);
    float4 b0 = *(const float4*)(rB);
    float4 b1 = *(const float4*)(rB + 4);
    acc[0] += wA * a0.x + wB * b0.x;
    acc[1] += wA * a0.y + wB * b0.y;
    acc[2] += wA * a0.z + wB * b0.z;
    acc[3] += wA * a0.w + wB * b0.w;
    acc[4] += wA * a1.x + wB * b1.x;
    acc[5] += wA * a1.y + wB * b1.y;
    acc[6] += wA * a1.z + wB * b1.z;
    acc[7] += wA * a1.w + wB * b1.w;
  }
  if (j + 4 <= end) {
    int sA = csr_src[j + q];
    float wA = exw[j + q] * inv;
    const float* rA = Hl + (size_t)sA * 128;
    float4 a0 = *(const float4*)(rA);
    float4 a1 = *(const float4*)(rA + 4);
    acc[0] += wA * a0.x; acc[1] += wA * a0.y; acc[2] += wA * a0.z; acc[3] += wA * a0.w;
    acc[4] += wA * a1.x; acc[5] += wA * a1.y; acc[6] += wA * a1.z; acc[7] += wA * a1.w;
    j += 4;
  }
  if (j + q < end) {
    int sA = csr_src[j + q];
    float wA = exw[j + q] * inv;
    const float* rA = Hl + (size_t)sA * 128;
    float4 a0 = *(const float4*)(rA);
    float4 a1 = *(const float4*)(rA + 4);
    acc[0] += wA * a0.x; acc[1] += wA * a0.y; acc[2] += wA * a0.z; acc[3] += wA * a0.w;
    acc[4] += wA * a1.x; acc[5] += wA * a1.y; acc[6] += wA * a1.z; acc[7] += wA * a1.w;
  }
#pragma unroll
  for (int c = 0; c < 8; ++c) {
    acc[c] += __shfl_xor(acc[c], 16);
    acc[c] += __shfl_xor(acc[c], 32);
  }
  if (q == 0) {
    float4 bv0 = *(const float4*)(bias + l * 8);
    float4 bv1 = *(const float4*)(bias + l * 8 + 4);
    float4 o0 = make_float4(acc[0] + bv0.x, acc[1] + bv0.y, acc[2] + bv0.z, acc[3] + bv0.w);
    float4 o1 = make_float4(acc[4] + bv1.x, acc[5] + bv1.y, acc[6] + bv1.z, acc[7] + bv1.w);
    if (relu) {
      o0.x = fmaxf(o0.x, 0.f); o0.y = fmaxf(o0.y, 0.f); o0.z = fmaxf(o0.z, 0.f); o0.w = fmaxf(o0.w, 0.f);
      o1.x = fmaxf(o1.x, 0.f); o1.y = fmaxf(o1.y, 0.f); o1.z = fmaxf(o1.z, 0.f); o1.w = fmaxf(o1.w, 0.f);
    }
    *(float4*)(Yout + (size_t)dst * 128 + l * 8) = o0;
    *(float4*)(Yout + (size_t)dst * 128 + l * 8 + 4) = o1;
  }
}

// run-length pooling over sorted batch
__global__ __launch_bounds__(256) void k_pool(const float* __restrict__ Hh,
                                              const int* __restrict__ batch,
                                              float* __restrict__ gsum,
                                              float* __restrict__ gcnt,
                                              int N, int nwaves) {
  int gw = (blockIdx.x * 256 + threadIdx.x) >> 6;
  int lane = threadIdx.x & 63;
  int chunk = (N + nwaves - 1) / nwaves;
  int beg = gw * chunk;
  int end = beg + chunk; if (end > N) end = N;
  if (beg >= end) return;

  int curg = batch[beg];
  float2 acc = {0.f, 0.f};
  int cnt = 0;
  for (int n = beg; n < end; ++n) {
    int g = batch[n];
    if (g != curg) {
      atomicAdd(&gsum[curg * 128 + lane * 2], acc.x);
      atomicAdd(&gsum[curg * 128 + lane * 2 + 1], acc.y);
      if (lane == 0) atomicAdd(&gcnt[curg], (float)cnt);
      acc.x = 0.f; acc.y = 0.f; cnt = 0; curg = g;
    }
    float2 h = *(const float2*)(Hh + (size_t)n * 128 + lane * 2);
    acc.x += h.x; acc.y += h.y; ++cnt;
  }
  atomicAdd(&gsum[curg * 128 + lane * 2], acc.x);
  atomicAdd(&gsum[curg * 128 + lane * 2 + 1], acc.y);
  if (lane == 0) atomicAdd(&gcnt[curg], (float)cnt);
}

__global__ __launch_bounds__(128) void k_final(const float* __restrict__ gsum,
                                               const float* __restrict__ gcnt,
                                               const float* __restrict__ Wlin,
                                               const float* __restrict__ blin,
                                               float* __restrict__ out) {
  int t = threadIdx.x;  // 128 threads: (g, c) pairs
  int g = t >> 1, c = t & 1;
  float inv = 1.0f / fmaxf(gcnt[g], 1.0f);
  float acc = blin[c];
  for (int k = 0; k < 128; ++k) acc += gsum[g * 128 + k] * inv * Wlin[k * 2 + c];
  out[g * 2 + c] = acc;
}

extern "C" void kernel_launch(void* const* d_in, const int* in_sizes, int n_in,
                              void* d_out, int out_size, void* d_ws, size_t ws_size,
                              hipStream_t stream) {
  const float* x    = (const float*)d_in[0];
  const int*   ei   = (const int*)d_in[1];
  const int*   batch= (const int*)d_in[2];
  const float* W1   = (const float*)d_in[3];
  const float* as1  = (const float*)d_in[4];
  const float* ad1  = (const float*)d_in[5];
  const float* b1   = (const float*)d_in[6];
  const float* W2   = (const float*)d_in[7];
  const float* as2  = (const float*)d_in[8];
  const float* ad2  = (const float*)d_in[9];
  const float* b2   = (const float*)d_in[10];
  const float* W3   = (const float*)d_in[11];
  const float* as3  = (const float*)d_in[12];
  const float* ad3  = (const float*)d_in[13];
  const float* b3   = (const float*)d_in[14];
  const float* Wlin = (const float*)d_in[15];
  const float* blin = (const float*)d_in[16];

  int N = in_sizes[0] / 4;
  int E = in_sizes[1] / 2;
  int ET = E + N;

  char* ws = (char*)d_ws;
  float* bufA = (float*)ws; ws += (size_t)N * 128 * 4;
  float* bufB = (float*)ws; ws += (size_t)N * 128 * 4;
  float* al_s = (float*)ws; ws += (size_t)N * 4;
  float* al_d = (float*)ws; ws += (size_t)N * 4;
  float* gsum = (float*)ws; ws += (size_t)64 * 128 * 4;
  float* gcnt = (float*)ws; ws += (size_t)64 * 4;
  int* rowp   = (int*)ws;   ws += (size_t)(N + 1) * 4;
  int* cursor = (int*)ws;   ws += (size_t)N * 4;
  int* csr    = (int*)ws;   ws += (size_t)ET * 4;
  float* exw  = (float*)ws; ws += (size_t)ET * 4;
  int* bsum   = (int*)ws;   ws += (size_t)256 * 4;

  hipMemsetAsync(cursor, 0, (size_t)N * 4, stream);
  hipMemsetAsync(gsum, 0, (size_t)(64 * 128 + 64) * 4, stream);  // gsum + gcnt

  int eb = (ET + 255) / 256;
  int nsb = (N + 1023) / 1024;  // scan blocks (<=256)
  k_count  <<<eb, 256, 0, stream>>>(ei, cursor, E, N);
  k_scan1  <<<nsb, 256, 0, stream>>>(cursor, rowp, bsum, N);
  k_scan2  <<<1, 256, 0, stream>>>(bsum, nsb);
  k_scan3  <<<nsb, 256, 0, stream>>>(rowp, cursor, bsum, N, ET);
  k_scatter<<<eb, 256, 0, stream>>>(ei, cursor, csr, E, N);

  int nb4 = (N + 3) / 4;
  // layer 1
  k_gemm4al<<<nb4, 256, 0, stream>>>(x, W1, as1, ad1, bufA, al_s, al_d, N);
  k_agg    <<<nb4, 256, 0, stream>>>(csr, rowp, al_s, al_d, bufA, b1, exw, bufB, N, 1);
  // layer 2
  k_gemm128al<<<(N + 63) / 64, 256, 0, stream>>>(bufB, W2, as2, ad2, bufA, al_s, al_d, N);
  k_agg      <<<nb4, 256, 0, stream>>>(csr, rowp, al_s, al_d, bufA, b2, exw, bufB, N, 1);
  // layer 3
  k_gemm128al<<<(N + 63) / 64, 256, 0, stream>>>(bufB, W3, as3, ad3, bufA, al_s, al_d, N);
  k_agg      <<<nb4, 256, 0, stream>>>(csr, rowp, al_s, al_d, bufA, b3, exw, bufB, N, 0);

  // global mean pool + linear head (256 blocks x 4 waves = 1024 waves)
  k_pool <<<256, 256, 0, stream>>>(bufB, batch, gsum, gcnt, N, 1024);
  k_final<<<1, 128, 0, stream>>>(gsum, gcnt, Wlin, blin, (float*)d_out);
}